// Round 3
// baseline (369.324 us; speedup 1.0000x reference)
//
#include <hip/hip_runtime.h>
#include <math.h>

#define Mn 4096
#define Dn 64
#define MUA_STRIDE 4104

// ---- workspace offsets (in floats) ----
// A2/K are dead after k4; CRIT (k5..k6) overlaps them.
#define OFF_A2   0                  /* k1..k3 */
#define OFF_CRIT 0                  /* k5..k6, 4097 floats (overlaps A2 + K[0]) */
#define OFF_K    4096               /* k1..k4 */
#define OFF_Q    8192
#define OFF_H    12288
#define OFF_MUA  16384              /* 4 x MUA_STRIDE = 16416 */
#define OFF_QS   32800
#define OFF_QSD  36896
#define SC_PU    40992
#define SC_INVPU 40993
#define SC_NPV   40994
#define SC_PV    40995
#define SC_INVPV 40996
#define SC_DENOM 40997
#define SC_PRUNE 40998              /* int slot */
#define OFF_DICTB 49152             /* 4096x64 bf16 = 131072 floats */

// ---- output offsets (in floats) ----
#define O_MU   0
#define O_SIG  16384
#define O_Q    16793600
#define O_DICT 33570816
#define O_TI   33832960
#define O_NNUM 33837056
#define O_NDEN 33837060

typedef __attribute__((ext_vector_type(8))) __bf16 bf16x8;
typedef __attribute__((ext_vector_type(4))) float f32x4;

__device__ __forceinline__ float waveReduceSum(float v) {
#pragma unroll
    for (int o = 32; o > 0; o >>= 1) v += __shfl_down(v, o);
    return v;
}

__device__ __forceinline__ unsigned short f2bf_rne(float f) {
    unsigned u = __float_as_uint(f);
    unsigned r = (u + 0x7FFFu + ((u >> 16) & 1u)) >> 16;
    return (unsigned short)r;
}

// K1: a2[i] = |d_i|^2 ; k[i] = exp(-max(|d_i|^2+|x|^2-2 d_i.x,0)/128) * alloc_i
//     also: dictb = bf16(dict) for the MFMA Kdd paths (Kdd weight = 0.001 ->
//     bf16 rounding contributes ~1e-6 absolute to sig; verified passing).
__global__ void k1_prep(const float* __restrict__ dict, const float* __restrict__ x,
                        const float* __restrict__ ti, float* __restrict__ ws) {
    int row  = blockIdx.x * 4 + (threadIdx.x >> 6);
    int lane = threadIdx.x & 63;
    float d  = dict[row * Dn + lane];
    float xv = x[lane];
    ((unsigned short*)(ws + OFF_DICTB))[row * Dn + lane] = f2bf_rne(d);
    float a2 = waveReduceSum(d * d);
    float x2 = waveReduceSum(xv * xv);
    float dx = waveReduceSum(d * xv);
    if (lane == 0) {
        ws[OFF_A2 + row] = a2;
        float d2 = fmaxf(a2 + x2 - 2.0f * dx, 0.0f);
        float kv = expf(d2 * (-1.0f / 128.0f));
        ws[OFF_K + row] = (ti[row] >= 0.0f) ? kv : 0.0f;
    }
}

// K2: q = Q @ k ; also zero h
__global__ void k2_q(const float* __restrict__ Q, float* __restrict__ ws) {
    __shared__ float red[4];
    const int row = blockIdx.x;
    const int tid = threadIdx.x;
    const float4* Qr = (const float4*)(Q + (size_t)row * Mn);
    const float4* kv = (const float4*)(ws + OFF_K);
    float s = 0.0f;
#pragma unroll
    for (int it = 0; it < 4; ++it) {
        int u = tid + it * 256;
        float4 a = Qr[u], b = kv[u];
        s += a.x * b.x + a.y * b.y + a.z * b.z + a.w * b.w;
    }
    s = waveReduceSum(s);
    if ((tid & 63) == 0) red[tid >> 6] = s;
    __syncthreads();
    if (tid == 0) {
        ws[OFF_Q + row] = red[0] + red[1] + red[2] + red[3];
        ws[OFF_H + row] = 0.0f;
    }
}

// K3 (role-split, one launch): h = 0.999*(sigma @ q) + 0.001*(Kdd_masked @ q).
//  blocks [0,1024):    BW-bound sigma-GEMV, one row per wave, float4 streaming.
//  blocks [1024,2048): compute-bound Kdd-GEMV via bf16 MFMA; reads only the
//                      L2-resident dictb (512 KB) — no sigma, no stores.
// Mixing the two roles in one launch lets the Kdd compute hide under the
// sigma HBM stream. sig itself is never materialized (k7 recomputes it).
__global__ __launch_bounds__(256) void k3_h(
        const float* __restrict__ sigma, const float* __restrict__ ti,
        float* __restrict__ ws) {
    const int tid  = threadIdx.x;
    const int lane = tid & 63;
    const int w    = tid >> 6;

    if (blockIdx.x < 1024) {
        // ---- sigma GEMV: row = blockIdx.x*4 + w ----
        const int row = blockIdx.x * 4 + w;
        const float4* S  = (const float4*)(sigma + (size_t)row * Mn);
        const float4* q4 = (const float4*)(ws + OFF_Q);
        float s = 0.0f;
#pragma unroll
        for (int it = 0; it < 16; ++it) {
            int u = lane + it * 64;
            float4 a = S[u], b = q4[u];
            s += a.x * b.x + a.y * b.y + a.z * b.z + a.w * b.w;
        }
        s = waveReduceSum(s);
        if (lane == 0) atomicAdd(ws + OFF_H + row, 0.999f * s);
        return;
    }

    // ---- Kdd GEMV via MFMA: tile t = blockIdx.x - 1024 ----
    const int t  = blockIdx.x - 1024;
    const int i0 = (t >> 5) * 128 + (w >> 1) * 64;
    const int j0 = (t & 31) * 128 + (w & 1) * 64;
    const int lr = lane >> 4;
    const int lc = lane & 15;
    const uint4* db = (const uint4*)(ws + OFF_DICTB);

    bf16x8 bfrag[4][2];
    float a2j[4], qmj[4];
#pragma unroll
    for (int jt = 0; jt < 4; ++jt) {
        const int col = j0 + jt * 16 + lc;
        bfrag[jt][0] = __builtin_bit_cast(bf16x8, db[col * 8 + lr]);
        bfrag[jt][1] = __builtin_bit_cast(bf16x8, db[col * 8 + 4 + lr]);
        a2j[jt] = ws[OFF_A2 + col];
        float alj = (ti[col] >= 0.0f) ? 1.0f : 0.0f;
        qmj[jt] = 0.001f * alj * ws[OFF_Q + col];
    }

#pragma unroll
    for (int it = 0; it < 4; ++it) {
        const int arow = i0 + it * 16 + lc;
        bf16x8 af0 = __builtin_bit_cast(bf16x8, db[arow * 8 + lr]);
        bf16x8 af1 = __builtin_bit_cast(bf16x8, db[arow * 8 + 4 + lr]);
        float hacc[4] = {0.f, 0.f, 0.f, 0.f};
        float a2i[4], ali[4];
#pragma unroll
        for (int i = 0; i < 4; ++i) {
            const int rg = i0 + it * 16 + lr * 4 + i;
            a2i[i] = ws[OFF_A2 + rg];
            ali[i] = (ti[rg] >= 0.0f) ? 1.0f : 0.0f;
        }
#pragma unroll
        for (int jt = 0; jt < 4; ++jt) {
            f32x4 acc = {0.0f, 0.0f, 0.0f, 0.0f};
            acc = __builtin_amdgcn_mfma_f32_16x16x32_bf16(af0, bfrag[jt][0], acc, 0, 0, 0);
            acc = __builtin_amdgcn_mfma_f32_16x16x32_bf16(af1, bfrag[jt][1], acc, 0, 0, 0);
#pragma unroll
            for (int i = 0; i < 4; ++i) {
                float d2 = fmaxf(a2i[i] + a2j[jt] - 2.0f * acc[i], 0.0f);
                float kv = __expf(d2 * (-1.0f / 128.0f)) * ali[i];
                hacc[i] = fmaf(kv, qmj[jt], hacc[i]);
            }
        }
#pragma unroll
        for (int i = 0; i < 4; ++i) {
            float v = hacc[i];
            v += __shfl_xor(v, 1);
            v += __shfl_xor(v, 2);
            v += __shfl_xor(v, 4);
            v += __shfl_xor(v, 8);
            if (lc == i) atomicAdd(ws + OFF_H + i0 + it * 16 + lr * 4 + i, v);
        }
    }
}

__device__ __forceinline__ float blockReduce1024(float v, float* sred) {
    v = waveReduceSum(v);
    int tid = threadIdx.x;
    __syncthreads();
    if ((tid & 63) == 0) sred[tid >> 6] = v;
    __syncthreads();
    float r = 0.0f;
    if (tid == 0) {
#pragma unroll
        for (int i = 0; i < 16; ++i) r += sred[i];
    }
    return r;
}

// K4: scalars pu/npv/pv, pred_mean, nnum/nden, mu_a
__global__ __launch_bounds__(1024) void k4_scalars(
        const float* __restrict__ mu, const float* __restrict__ y,
        const float* __restrict__ nn, const float* __restrict__ nd,
        float* __restrict__ ws, float* __restrict__ out) {
    __shared__ float sred[16];
    __shared__ float sb[8];
    const int tid = threadIdx.x;
    const float* k = ws + OFF_K;
    const float* q = ws + OFF_Q;
    const float* h = ws + OFF_H;
    float kq = 0, qh = 0, p0 = 0, p1 = 0, p2 = 0, p3 = 0;
    for (int i = tid; i < Mn; i += 1024) {
        float qi = q[i];
        kq += k[i] * qi;
        qh += qi * h[i];
        p0 += qi * mu[0 * Mn + i];
        p1 += qi * mu[1 * Mn + i];
        p2 += qi * mu[2 * Mn + i];
        p3 += qi * mu[3 * Mn + i];
    }
    float rkq = blockReduce1024(kq, sred);
    float rqh = blockReduce1024(qh, sred);
    float r0 = blockReduce1024(p0, sred);
    float r1 = blockReduce1024(p1, sred);
    float r2 = blockReduce1024(p2, sred);
    float r3 = blockReduce1024(p3, sred);
    if (tid == 0) {
        const float sf = sqrtf(0.999f);
        float pu  = fmaxf(1.0f - rkq, 0.0f);      // K_xx = 1 + 1e-10 == 1.0f in fp32
        float npv = fmaxf(pu + rqh, 0.0f);
        float pv  = 0.01f + npv;
        ws[SC_PU] = pu;
        ws[SC_INVPU] = 1.0f / pu;
        ws[SC_NPV] = npv;
        ws[SC_PV] = pv;
        ws[SC_INVPV] = 1.0f / pv;
        float pm[4] = {sf * r0, sf * r1, sf * r2, sf * r3};
#pragma unroll
        for (int yd = 0; yd < 4; ++yd) {
            float yv = y[yd];
            float dy = yv - pm[yd];
            float dl = dy / pv;
            sb[yd] = dl;
            ws[OFF_MUA + yd * MUA_STRIDE + Mn] = pm[yd] + dl * npv;
            out[O_NNUM + yd] = nn[yd] + 0.999f * (dy * dy) / pv;
        }
        out[O_NDEN] = nd[0] + 0.999f;
    }
    __syncthreads();
    const float sf = sqrtf(0.999f);
    float d0 = sb[0], d1 = sb[1], d2 = sb[2], d3 = sb[3];
    for (int i = tid; i < Mn; i += 1024) {
        float hi = h[i];
        ws[OFF_MUA + 0 * MUA_STRIDE + i] = sf * mu[0 * Mn + i] + d0 * hi;
        ws[OFF_MUA + 1 * MUA_STRIDE + i] = sf * mu[1 * Mn + i] + d1 * hi;
        ws[OFF_MUA + 2 * MUA_STRIDE + i] = sf * mu[2 * Mn + i] + d2 * hi;
        ws[OFF_MUA + 3 * MUA_STRIDE + i] = sf * mu[3 * Mn + i] + d3 * hi;
    }
}

// K5: criterion rows — one block (256 thr) per row, float4 streams
__global__ __launch_bounds__(256) void k5_crit(const float* __restrict__ Q,
                                               const float* __restrict__ ti,
                                               float* __restrict__ ws) {
    __shared__ float sred[4][4];
    const int row = blockIdx.x;       // 0..Mn
    const int tid = threadIdx.x;
    const float pu = ws[SC_PU];
    if (pu < 1e-10f) {
        if (tid == 0) ws[OFF_CRIT + row] = (row < Mn) ? 1.0f : 0.0f;
        return;
    }
    const float inv_pu = ws[SC_INVPU];
    const bool rin = (row < Mn);
    const float p2i = rin ? ws[OFF_Q + row] : -1.0f;
    const float4* q4  = (const float4*)(ws + OFF_Q);
    const float4* Qr4 = (const float4*)(Q + (size_t)row * Mn);  // deref only if rin
    const float* mua = ws + OFF_MUA;
    float n0 = 0, n1 = 0, n2 = 0, n3 = 0;
#pragma unroll
    for (int it = 0; it < 4; ++it) {
        int u = tid + it * 256;
        float4 qv = q4[u];
        float4 base = rin ? Qr4[u] : make_float4(0.f, 0.f, 0.f, 0.f);
        float4 qa;
        qa.x = base.x + p2i * qv.x * inv_pu;
        qa.y = base.y + p2i * qv.y * inv_pu;
        qa.z = base.z + p2i * qv.z * inv_pu;
        qa.w = base.w + p2i * qv.w * inv_pu;
        const float4 m0 = *(const float4*)(mua + 0 * MUA_STRIDE + u * 4);
        const float4 m1 = *(const float4*)(mua + 1 * MUA_STRIDE + u * 4);
        const float4 m2 = *(const float4*)(mua + 2 * MUA_STRIDE + u * 4);
        const float4 m3 = *(const float4*)(mua + 3 * MUA_STRIDE + u * 4);
        n0 += qa.x * m0.x + qa.y * m0.y + qa.z * m0.z + qa.w * m0.w;
        n1 += qa.x * m1.x + qa.y * m1.y + qa.z * m1.z + qa.w * m1.w;
        n2 += qa.x * m2.x + qa.y * m2.y + qa.z * m2.z + qa.w * m2.w;
        n3 += qa.x * m3.x + qa.y * m3.y + qa.z * m3.z + qa.w * m3.w;
    }
    n0 = waveReduceSum(n0);
    n1 = waveReduceSum(n1);
    n2 = waveReduceSum(n2);
    n3 = waveReduceSum(n3);
    if ((tid & 63) == 0) {
        int w = tid >> 6;
        sred[w][0] = n0; sred[w][1] = n1; sred[w][2] = n2; sred[w][3] = n3;
    }
    __syncthreads();
    if (tid == 0) {
        float t0 = 0, t1 = 0, t2 = 0, t3 = 0;
#pragma unroll
        for (int w = 0; w < 4; ++w) {
            t0 += sred[w][0]; t1 += sred[w][1]; t2 += sred[w][2]; t3 += sred[w][3];
        }
        // j = Mn term: p2j = -1, base = 0
        float qaM = -p2i * inv_pu;
        t0 += qaM * mua[0 * MUA_STRIDE + Mn];
        t1 += qaM * mua[1 * MUA_STRIDE + Mn];
        t2 += qaM * mua[2 * MUA_STRIDE + Mn];
        t3 += qaM * mua[3 * MUA_STRIDE + Mn];
        bool xa = rin ? (ti[row] >= 0.0f) : true;
        float crit = 0.0f;
        if (xa) {
            float dq = rin ? (Q[(size_t)row * Mn + row] + p2i * p2i * inv_pu) : inv_pu;
            crit = fabsf(t0 / dq) + fabsf(t1 / dq) + fabsf(t2 / dq) + fabsf(t3 / dq);
        }
        ws[OFF_CRIT + row] = crit;
    }
}

// K6: argmin (first occurrence) -> prune, denom
__global__ __launch_bounds__(1024) void k6_argmin(const float* __restrict__ Q,
                                                  const float* __restrict__ ti,
                                                  float* __restrict__ ws) {
    __shared__ float sval[1024];
    __shared__ int   sidx[1024];
    const int tid = threadIdx.x;
    float bv = INFINITY;
    int bi = Mn + 1;
    for (int i = tid; i <= Mn; i += 1024) {
        float v = ws[OFF_CRIT + i];
        if (v < bv) { bv = v; bi = i; }
    }
    sval[tid] = bv; sidx[tid] = bi;
    __syncthreads();
    for (int s = 512; s > 0; s >>= 1) {
        if (tid < s) {
            float ov = sval[tid + s]; int oi = sidx[tid + s];
            if (ov < sval[tid] || (ov == sval[tid] && oi < sidx[tid])) {
                sval[tid] = ov; sidx[tid] = oi;
            }
        }
        __syncthreads();
    }
    if (tid == 0) {
        int prune = sidx[0];
        ((int*)ws)[SC_PRUNE] = prune;
        float inv_pu = ws[SC_INVPU];
        bool xa = (prune == Mn) ? true : (ti[prune] >= 0.0f);
        float qap;
        if (prune < Mn) {
            float qp = ws[OFF_Q + prune];
            qap = Q[(size_t)prune * Mn + prune] + qp * qp * inv_pu;
        } else {
            qap = inv_pu;  // Q_a[M,M] = (-1)(-1)/pu
        }
        ws[SC_DENOM] = xa ? qap : INFINITY;
    }
}

// K6b: dict_n, ti_n, Qs, Qsd
__global__ void k6b_vec(const float* __restrict__ Q, const float* __restrict__ dict,
                        const float* __restrict__ x, const float* __restrict__ ti,
                        const int* __restrict__ tptr, float* __restrict__ ws,
                        float* __restrict__ out) {
    const int tid = blockIdx.x * 256 + threadIdx.x;
    const int prune = ((const int*)ws)[SC_PRUNE];
    const int row = tid >> 6, col = tid & 63;
    out[O_DICT + tid] = (row == prune) ? x[col] : dict[tid];
    if (tid < Mn) {
        float tv = ti[tid];
        if (tid == prune) {
            int raw = *tptr;  // hedge: accept either int32 or float32-encoded t
            tv = (raw >= 0 && raw < (1 << 30)) ? (float)raw : __int_as_float(raw);
        }
        out[O_TI + tid] = tv;
        const float inv_pu = ws[SC_INVPU];
        const float denom  = ws[SC_DENOM];
        const float p2p = (prune < Mn) ? ws[OFF_Q + prune] : -1.0f;
        float qs;
        if (tid == prune) {
            qs = -p2p * inv_pu;  // Q_a[M, prune]
        } else {
            float base = (prune < Mn) ? Q[(size_t)tid * Mn + prune] : 0.0f;
            qs = base + ws[OFF_Q + tid] * p2p * inv_pu;
        }
        ws[OFF_QS + tid] = qs;
        ws[OFF_QSD + tid] = qs / denom;
    }
}

// K7 (role-split, one launch):
//  blocks [0,4096):  Q_n row i + mu_n (as before, minus the sig pass).
//  blocks [4096,5120): sig_n 128x128 tiles — recompute sig = 0.999*sigma +
//     0.001*Kdd(masked, bf16 MFMA from dictb) on the fly, apply the rank-1
//     downdate and permutation/mask. The k3-era intermediate sig matrix is
//     never written or re-read (-128 MB HBM round trip).
__global__ __launch_bounds__(256) void k7_fused(const float* __restrict__ Q,
                                                const float* __restrict__ sigma,
                                                const float* __restrict__ ti,
                                                float* __restrict__ out,
                                                const float* __restrict__ ws) {
    const int tid = threadIdx.x;
    const int prune = ((const int*)ws)[SC_PRUNE];
    const float inv_pu = ws[SC_INVPU];
    const float inv_pv = ws[SC_INVPV];
    const float npv = ws[SC_NPV];

    if (blockIdx.x < 4096) {
        const int i = blockIdx.x;
        // ---- Q_n row ----
        const int pi = (i == prune) ? Mn : i;
        const bool piok = (pi < Mn);
        const float p2i = piok ? ws[OFF_Q + pi] : -1.0f;
        const float qsi = ws[OFF_QS + i];
        const float4* Qr4  = (const float4*)(Q + (size_t)pi * Mn);   // deref only if piok
        const float4* q4   = (const float4*)(ws + OFF_Q);
        const float4* qsd4 = (const float4*)(ws + OFF_QSD);
        float4* o4 = (float4*)(out + O_Q + (size_t)i * Mn);
#pragma unroll
        for (int it = 0; it < 4; ++it) {
            int u = tid + it * 256;
            float4 base = piok ? Qr4[u] : make_float4(0.f, 0.f, 0.f, 0.f);
            float4 p2j = q4[u];
            if ((prune >> 2) == u) {     // prune < Mn lands in some u; prune==Mn never
                int c = prune & 3;
                ((float*)&p2j)[c] = -1.0f;
                ((float*)&base)[c] = 0.0f;
            }
            float4 d = qsd4[u];
            float4 r;
            r.x = base.x + p2i * p2j.x * inv_pu - qsi * d.x;
            r.y = base.y + p2i * p2j.y * inv_pu - qsi * d.y;
            r.z = base.z + p2i * p2j.z * inv_pu - qsi * d.z;
            r.w = base.w + p2i * p2j.w * inv_pu - qsi * d.w;
            o4[u] = r;
        }
        // ---- mu_n (4 values for this row) ----
        if (tid < 4) {
            float tin = out[O_TI + i];
            float v;
            if (tin < 0.0f) v = 0.0f;
            else v = ws[OFF_MUA + tid * MUA_STRIDE + ((i == prune) ? Mn : i)];
            out[O_MU + tid * Mn + i] = v;
        }
        return;
    }

    // ---- sig_n tile ----
    const int t    = blockIdx.x - 4096;
    const int lane = tid & 63;
    const int w    = tid >> 6;
    const int i0 = (t >> 5) * 128 + (w >> 1) * 64;
    const int j0 = (t & 31) * 128 + (w & 1) * 64;
    const int lr = lane >> 4;
    const int lc = lane & 15;
    const uint4* db = (const uint4*)(ws + OFF_DICTB);

    bf16x8 bfrag[4][2];
    float a2j[4], hj[4], aljo[4], ajn[4];
    bool pcol[4];
#pragma unroll
    for (int jt = 0; jt < 4; ++jt) {
        const int col = j0 + jt * 16 + lc;
        bfrag[jt][0] = __builtin_bit_cast(bf16x8, db[col * 8 + lr]);
        bfrag[jt][1] = __builtin_bit_cast(bf16x8, db[col * 8 + 4 + lr]);
        a2j[jt]  = ws[OFF_A2 + col];
        hj[jt]   = ws[OFF_H + col];
        aljo[jt] = (ti[col] >= 0.0f) ? 1.0f : 0.0f;         // old alloc (Kdd mask)
        ajn[jt]  = (out[O_TI + col] >= 0.0f) ? 1.0f : 0.0f; // new alloc (final mask)
        pcol[jt] = (col == prune);
    }

#pragma unroll
    for (int it = 0; it < 4; ++it) {
        const int arow = i0 + it * 16 + lc;
        bf16x8 af0 = __builtin_bit_cast(bf16x8, db[arow * 8 + lr]);
        bf16x8 af1 = __builtin_bit_cast(bf16x8, db[arow * 8 + 4 + lr]);
        float a2i[4], alio[4], ain[4], hr[4];
        bool prow[4];
#pragma unroll
        for (int i = 0; i < 4; ++i) {
            const int rg = i0 + it * 16 + lr * 4 + i;
            a2i[i]  = ws[OFF_A2 + rg];
            alio[i] = (ti[rg] >= 0.0f) ? 1.0f : 0.0f;
            ain[i]  = (out[O_TI + rg] >= 0.0f) ? 1.0f : 0.0f;
            hr[i]   = ws[OFF_H + rg];
            prow[i] = (rg == prune);
        }
#pragma unroll
        for (int jt = 0; jt < 4; ++jt) {
            f32x4 acc = {0.0f, 0.0f, 0.0f, 0.0f};
            acc = __builtin_amdgcn_mfma_f32_16x16x32_bf16(af0, bfrag[jt][0], acc, 0, 0, 0);
            acc = __builtin_amdgcn_mfma_f32_16x16x32_bf16(af1, bfrag[jt][1], acc, 0, 0, 0);
            const int colg = j0 + jt * 16 + lc;
#pragma unroll
            for (int i = 0; i < 4; ++i) {
                const int rg = i0 + it * 16 + lr * 4 + i;
                const size_t off = (size_t)rg * Mn + colg;
                float sv = sigma[off];
                float d2 = fmaxf(a2i[i] + a2j[jt] - 2.0f * acc[i], 0.0f);
                float kv = __expf(d2 * (-1.0f / 128.0f)) * alio[i] * aljo[jt];
                float bs = 0.999f * sv + 0.001f * kv;         // sig_a[rg][colg], normal
                if (pcol[jt]) bs = prow[i] ? npv : hr[i];     // col -> M
                if (prow[i])  bs = pcol[jt] ? npv : hj[jt];   // row -> M
                float p_i = prow[i]  ? npv : hr[i];
                float p_j = pcol[jt] ? npv : hj[jt];
                float r = ain[i] * ajn[jt] * (bs - p_i * p_j * inv_pv);
                out[O_SIG + off] = r;
            }
        }
    }
}

extern "C" void kernel_launch(void* const* d_in, const int* in_sizes, int n_in,
                              void* d_out, int out_size, void* d_ws, size_t ws_size,
                              hipStream_t stream) {
    const float* dict  = (const float*)d_in[0];
    const float* mu    = (const float*)d_in[1];
    const float* sigma = (const float*)d_in[2];
    const float* Q     = (const float*)d_in[3];
    const float* x     = (const float*)d_in[4];
    const float* y     = (const float*)d_in[5];
    const float* nn    = (const float*)d_in[6];
    const float* nd    = (const float*)d_in[7];
    const float* ti    = (const float*)d_in[8];
    const int*   tptr  = (const int*)d_in[9];
    float* out = (float*)d_out;
    float* ws  = (float*)d_ws;

    k1_prep<<<1024, 256, 0, stream>>>(dict, x, ti, ws);
    k2_q<<<4096, 256, 0, stream>>>(Q, ws);
    k3_h<<<2048, 256, 0, stream>>>(sigma, ti, ws);
    k4_scalars<<<1, 1024, 0, stream>>>(mu, y, nn, nd, ws, out);
    k5_crit<<<4097, 256, 0, stream>>>(Q, ti, ws);
    k6_argmin<<<1, 1024, 0, stream>>>(Q, ti, ws);
    k6b_vec<<<1024, 256, 0, stream>>>(Q, dict, x, ti, tptr, ws, out);
    k7_fused<<<5120, 256, 0, stream>>>(Q, sigma, ti, out, ws);
}

// Round 4
// 337.082 us; speedup vs baseline: 1.0956x; 1.0956x over previous
//
#include <hip/hip_runtime.h>
#include <math.h>

#define Mn 4096
#define Dn 64

// ---- workspace offsets (in floats) ----
#define OFF_A2   0                  /* k1..k7 (k7 sig role reads it!) */
#define OFF_K    4096               /* k1..k4 */
#define OFF_Q    8192
#define OFF_H    12288
#define OFF_CRIT 20480              /* 4097 floats, k4..k6 — moved off A2 (round-3 overlap bug) */
#define OFF_QS   32800
#define OFF_QSD  36896
#define SC_PU    40992
#define SC_INVPU 40993
#define SC_NPV   40994
#define SC_PV    40995
#define SC_INVPV 40996
#define SC_DENOM 40997
#define SC_PRUNE 40998              /* int slot */
#define SC_DL    41000              /* 4 floats: (y-pm)/pv */
#define SC_VY    41004              /* 4 floats: p2^T mua_yd */
#define SC_MUAM  41008              /* 4 floats: mua_yd[Mn] */
#define OFF_DICTB 49152             /* 4096x64 bf16 = 131072 floats */

// ---- output offsets (in floats) ----
#define O_MU   0
#define O_SIG  16384
#define O_Q    16793600
#define O_DICT 33570816
#define O_TI   33832960
#define O_NNUM 33837056
#define O_NDEN 33837060

typedef __attribute__((ext_vector_type(8))) __bf16 bf16x8;
typedef __attribute__((ext_vector_type(4))) float f32x4;

__device__ __forceinline__ float waveReduceSum(float v) {
#pragma unroll
    for (int o = 32; o > 0; o >>= 1) v += __shfl_down(v, o);
    return v;
}

__device__ __forceinline__ unsigned short f2bf_rne(float f) {
    unsigned u = __float_as_uint(f);
    unsigned r = (u + 0x7FFFu + ((u >> 16) & 1u)) >> 16;
    return (unsigned short)r;
}

// K1: a2, k-vector, dictb (bf16 copy for MFMA Kdd)
__global__ void k1_prep(const float* __restrict__ dict, const float* __restrict__ x,
                        const float* __restrict__ ti, float* __restrict__ ws) {
    int row  = blockIdx.x * 4 + (threadIdx.x >> 6);
    int lane = threadIdx.x & 63;
    float d  = dict[row * Dn + lane];
    float xv = x[lane];
    ((unsigned short*)(ws + OFF_DICTB))[row * Dn + lane] = f2bf_rne(d);
    float a2 = waveReduceSum(d * d);
    float x2 = waveReduceSum(xv * xv);
    float dx = waveReduceSum(d * xv);
    if (lane == 0) {
        ws[OFF_A2 + row] = a2;
        float d2 = fmaxf(a2 + x2 - 2.0f * dx, 0.0f);
        float kv = expf(d2 * (-1.0f / 128.0f));
        ws[OFF_K + row] = (ti[row] >= 0.0f) ? kv : 0.0f;
    }
}

// K2: q = Q @ k ; zero h
__global__ void k2_q(const float* __restrict__ Q, float* __restrict__ ws) {
    __shared__ float red[4];
    const int row = blockIdx.x;
    const int tid = threadIdx.x;
    const float4* Qr = (const float4*)(Q + (size_t)row * Mn);
    const float4* kv = (const float4*)(ws + OFF_K);
    float s = 0.0f;
#pragma unroll
    for (int it = 0; it < 4; ++it) {
        int u = tid + it * 256;
        float4 a = Qr[u], b = kv[u];
        s += a.x * b.x + a.y * b.y + a.z * b.z + a.w * b.w;
    }
    s = waveReduceSum(s);
    if ((tid & 63) == 0) red[tid >> 6] = s;
    __syncthreads();
    if (tid == 0) {
        ws[OFF_Q + row] = red[0] + red[1] + red[2] + red[3];
        ws[OFF_H + row] = 0.0f;
    }
}

// K3: h = 0.999*(sigma@q) + 0.001*(Kdd_masked@q). Role-split as in round 3.
__global__ __launch_bounds__(256) void k3_h(
        const float* __restrict__ sigma, const float* __restrict__ ti,
        float* __restrict__ ws) {
    const int tid  = threadIdx.x;
    const int lane = tid & 63;
    const int w    = tid >> 6;

    if (blockIdx.x < 1024) {
        const int row = blockIdx.x * 4 + w;
        const float4* S  = (const float4*)(sigma + (size_t)row * Mn);
        const float4* q4 = (const float4*)(ws + OFF_Q);
        float s = 0.0f;
#pragma unroll
        for (int it = 0; it < 16; ++it) {
            int u = lane + it * 64;
            float4 a = S[u], b = q4[u];
            s += a.x * b.x + a.y * b.y + a.z * b.z + a.w * b.w;
        }
        s = waveReduceSum(s);
        if (lane == 0) atomicAdd(ws + OFF_H + row, 0.999f * s);
        return;
    }

    const int t  = blockIdx.x - 1024;
    const int i0 = (t >> 5) * 128 + (w >> 1) * 64;
    const int j0 = (t & 31) * 128 + (w & 1) * 64;
    const int lr = lane >> 4;
    const int lc = lane & 15;
    const uint4* db = (const uint4*)(ws + OFF_DICTB);

    bf16x8 bfrag[4][2];
    float a2j[4], qmj[4];
#pragma unroll
    for (int jt = 0; jt < 4; ++jt) {
        const int col = j0 + jt * 16 + lc;
        bfrag[jt][0] = __builtin_bit_cast(bf16x8, db[col * 8 + lr]);
        bfrag[jt][1] = __builtin_bit_cast(bf16x8, db[col * 8 + 4 + lr]);
        a2j[jt] = ws[OFF_A2 + col];
        float alj = (ti[col] >= 0.0f) ? 1.0f : 0.0f;
        qmj[jt] = 0.001f * alj * ws[OFF_Q + col];
    }

#pragma unroll
    for (int it = 0; it < 4; ++it) {
        const int arow = i0 + it * 16 + lc;
        bf16x8 af0 = __builtin_bit_cast(bf16x8, db[arow * 8 + lr]);
        bf16x8 af1 = __builtin_bit_cast(bf16x8, db[arow * 8 + 4 + lr]);
        float hacc[4] = {0.f, 0.f, 0.f, 0.f};
        float a2i[4], ali[4];
#pragma unroll
        for (int i = 0; i < 4; ++i) {
            const int rg = i0 + it * 16 + lr * 4 + i;
            a2i[i] = ws[OFF_A2 + rg];
            ali[i] = (ti[rg] >= 0.0f) ? 1.0f : 0.0f;
        }
#pragma unroll
        for (int jt = 0; jt < 4; ++jt) {
            f32x4 acc = {0.0f, 0.0f, 0.0f, 0.0f};
            acc = __builtin_amdgcn_mfma_f32_16x16x32_bf16(af0, bfrag[jt][0], acc, 0, 0, 0);
            acc = __builtin_amdgcn_mfma_f32_16x16x32_bf16(af1, bfrag[jt][1], acc, 0, 0, 0);
#pragma unroll
            for (int i = 0; i < 4; ++i) {
                float d2 = fmaxf(a2i[i] + a2j[jt] - 2.0f * acc[i], 0.0f);
                float kv = __expf(d2 * (-1.0f / 128.0f)) * ali[i];
                hacc[i] = fmaf(kv, qmj[jt], hacc[i]);
            }
        }
#pragma unroll
        for (int i = 0; i < 4; ++i) {
            float v = hacc[i];
            v += __shfl_xor(v, 1);
            v += __shfl_xor(v, 2);
            v += __shfl_xor(v, 4);
            v += __shfl_xor(v, 8);
            if (lc == i) atomicAdd(ws + OFF_H + i0 + it * 16 + lr * 4 + i, v);
        }
    }
}

__device__ __forceinline__ float blockReduce1024(float v, float* sred) {
    v = waveReduceSum(v);
    int tid = threadIdx.x;
    __syncthreads();
    if ((tid & 63) == 0) sred[tid >> 6] = v;
    __syncthreads();
    float r = 0.0f;
    if (tid == 0) {
#pragma unroll
        for (int i = 0; i < 16; ++i) r += sred[i];
    }
    return r;
}

// K4: all scalars. mua is NEVER materialized now — k5/k7 use (mu, h, dl, vy, muaM).
// crit[Mn] has closed form: pu<thr ? 0 : sum_yd |v_yd|.
__global__ __launch_bounds__(1024) void k4_scalars(
        const float* __restrict__ mu, const float* __restrict__ y,
        const float* __restrict__ nn, const float* __restrict__ nd,
        float* __restrict__ ws, float* __restrict__ out) {
    __shared__ float sred[16];
    const int tid = threadIdx.x;
    const float* k = ws + OFF_K;
    const float* q = ws + OFF_Q;
    const float* h = ws + OFF_H;
    float kq = 0, qh = 0, p0 = 0, p1 = 0, p2 = 0, p3 = 0;
    for (int i = tid; i < Mn; i += 1024) {
        float qi = q[i];
        kq += k[i] * qi;
        qh += qi * h[i];
        p0 += qi * mu[0 * Mn + i];
        p1 += qi * mu[1 * Mn + i];
        p2 += qi * mu[2 * Mn + i];
        p3 += qi * mu[3 * Mn + i];
    }
    float rkq = blockReduce1024(kq, sred);
    float rqh = blockReduce1024(qh, sred);
    float r0 = blockReduce1024(p0, sred);
    float r1 = blockReduce1024(p1, sred);
    float r2 = blockReduce1024(p2, sred);
    float r3 = blockReduce1024(p3, sred);
    if (tid == 0) {
        const float sf = sqrtf(0.999f);
        float pu  = fmaxf(1.0f - rkq, 0.0f);
        float npv = fmaxf(pu + rqh, 0.0f);
        float pv  = 0.01f + npv;
        ws[SC_PU] = pu;
        ws[SC_INVPU] = 1.0f / pu;
        ws[SC_NPV] = npv;
        ws[SC_PV] = pv;
        ws[SC_INVPV] = 1.0f / pv;
        float rr[4] = {r0, r1, r2, r3};
        float critM = 0.0f;
#pragma unroll
        for (int yd = 0; yd < 4; ++yd) {
            float pm = sf * rr[yd];
            float dy = y[yd] - pm;
            float dl = dy / pv;
            float muaM = pm + dl * npv;
            float vy   = (sf * rr[yd] + dl * rqh) - muaM;   // p2^T mua_yd
            ws[SC_DL + yd]   = dl;
            ws[SC_VY + yd]   = vy;
            ws[SC_MUAM + yd] = muaM;
            critM += fabsf(vy);
            out[O_NNUM + yd] = nn[yd] + 0.999f * (dy * dy) / pv;
        }
        out[O_NDEN] = nd[0] + 0.999f;
        ws[OFF_CRIT + Mn] = (pu < 1e-10f) ? 0.0f : critM;
    }
}

// K5: crit rows via rank-1 decomposition: Qa = Q + q q^T/pu (with p2=[q;-1]),
//   e_yd[r] = sf*(Q.mu_yd)[r] + dl_yd*(Q.h)[r] + (vy_yd/pu)*q[r]
//   crit[r] = xa ? sum_yd |e_yd/dq| : 0,  dq = Q[r][r] + q[r]^2/pu.
// One wave per row: 5 shared-pass dots over the row's 16KB Q stream.
// This removes round-3's 256 MB mua re-read amplification.
__global__ __launch_bounds__(256) void k5_crit(const float* __restrict__ Q,
                                               const float* __restrict__ mu,
                                               const float* __restrict__ ti,
                                               float* __restrict__ ws) {
    const int row  = blockIdx.x * 4 + (threadIdx.x >> 6);
    const int lane = threadIdx.x & 63;
    const float pu = ws[SC_PU];
    if (pu < 1e-10f) {
        if (lane == 0) ws[OFF_CRIT + row] = 1.0f;
        return;
    }
    const float4* Qr4 = (const float4*)(Q + (size_t)row * Mn);
    const float4* m04 = (const float4*)(mu + 0 * Mn);
    const float4* m14 = (const float4*)(mu + 1 * Mn);
    const float4* m24 = (const float4*)(mu + 2 * Mn);
    const float4* m34 = (const float4*)(mu + 3 * Mn);
    const float4* h4  = (const float4*)(ws + OFF_H);
    float am0 = 0, am1 = 0, am2 = 0, am3 = 0, ah = 0;
#pragma unroll
    for (int it = 0; it < 16; ++it) {
        int u = lane + it * 64;
        float4 qv = Qr4[u];
        float4 a0 = m04[u], a1 = m14[u], a2 = m24[u], a3 = m34[u], hh = h4[u];
        am0 += qv.x * a0.x + qv.y * a0.y + qv.z * a0.z + qv.w * a0.w;
        am1 += qv.x * a1.x + qv.y * a1.y + qv.z * a1.z + qv.w * a1.w;
        am2 += qv.x * a2.x + qv.y * a2.y + qv.z * a2.z + qv.w * a2.w;
        am3 += qv.x * a3.x + qv.y * a3.y + qv.z * a3.z + qv.w * a3.w;
        ah  += qv.x * hh.x + qv.y * hh.y + qv.z * hh.z + qv.w * hh.w;
    }
    am0 = waveReduceSum(am0);
    am1 = waveReduceSum(am1);
    am2 = waveReduceSum(am2);
    am3 = waveReduceSum(am3);
    ah  = waveReduceSum(ah);
    if (lane == 0) {
        const float inv_pu = ws[SC_INVPU];
        const float sf = sqrtf(0.999f);
        float qrow = ws[OFF_Q + row];
        float dq = Q[(size_t)row * Mn + row] + qrow * qrow * inv_pu;
        float crit = 0.0f;
        float am[4] = {am0, am1, am2, am3};
#pragma unroll
        for (int yd = 0; yd < 4; ++yd) {
            float e = sf * am[yd] + ws[SC_DL + yd] * ah + ws[SC_VY + yd] * inv_pu * qrow;
            crit += fabsf(e / dq);
        }
        bool xa = (ti[row] >= 0.0f);
        ws[OFF_CRIT + row] = xa ? crit : 0.0f;
    }
}

// K6: argmin (first occurrence) -> prune, denom
__global__ __launch_bounds__(1024) void k6_argmin(const float* __restrict__ Q,
                                                  const float* __restrict__ ti,
                                                  float* __restrict__ ws) {
    __shared__ float sval[1024];
    __shared__ int   sidx[1024];
    const int tid = threadIdx.x;
    float bv = INFINITY;
    int bi = Mn + 1;
    for (int i = tid; i <= Mn; i += 1024) {
        float v = ws[OFF_CRIT + i];
        if (v < bv) { bv = v; bi = i; }
    }
    sval[tid] = bv; sidx[tid] = bi;
    __syncthreads();
    for (int s = 512; s > 0; s >>= 1) {
        if (tid < s) {
            float ov = sval[tid + s]; int oi = sidx[tid + s];
            if (ov < sval[tid] || (ov == sval[tid] && oi < sidx[tid])) {
                sval[tid] = ov; sidx[tid] = oi;
            }
        }
        __syncthreads();
    }
    if (tid == 0) {
        int prune = sidx[0];
        ((int*)ws)[SC_PRUNE] = prune;
        float inv_pu = ws[SC_INVPU];
        bool xa = (prune == Mn) ? true : (ti[prune] >= 0.0f);
        float qap;
        if (prune < Mn) {
            float qp = ws[OFF_Q + prune];
            qap = Q[(size_t)prune * Mn + prune] + qp * qp * inv_pu;
        } else {
            qap = inv_pu;
        }
        ws[SC_DENOM] = xa ? qap : INFINITY;
    }
}

// K6b: dict_n, ti_n, Qs, Qsd
__global__ void k6b_vec(const float* __restrict__ Q, const float* __restrict__ dict,
                        const float* __restrict__ x, const float* __restrict__ ti,
                        const int* __restrict__ tptr, float* __restrict__ ws,
                        float* __restrict__ out) {
    const int tid = blockIdx.x * 256 + threadIdx.x;
    const int prune = ((const int*)ws)[SC_PRUNE];
    const int row = tid >> 6, col = tid & 63;
    out[O_DICT + tid] = (row == prune) ? x[col] : dict[tid];
    if (tid < Mn) {
        float tv = ti[tid];
        if (tid == prune) {
            int raw = *tptr;
            tv = (raw >= 0 && raw < (1 << 30)) ? (float)raw : __int_as_float(raw);
        }
        out[O_TI + tid] = tv;
        const float inv_pu = ws[SC_INVPU];
        const float denom  = ws[SC_DENOM];
        const float p2p = (prune < Mn) ? ws[OFF_Q + prune] : -1.0f;
        float qs;
        if (tid == prune) {
            qs = -p2p * inv_pu;
        } else {
            float base = (prune < Mn) ? Q[(size_t)tid * Mn + prune] : 0.0f;
            qs = base + ws[OFF_Q + tid] * p2p * inv_pu;
        }
        ws[OFF_QS + tid] = qs;
        ws[OFF_QSD + tid] = qs / denom;
    }
}

// K7 (role-split; sig tiles FIRST for longest-job-first scheduling):
//  blocks [0,1024): sig_n 128x128 tiles. MFMA operands SWAPPED (A=j-rows,
//    B=i-rows): by dict.dictT symmetry the C fragment lands at row=lane&15,
//    cols=(lane>>4)*4+reg — i.e. each lane holds 4 CONSECUTIVE columns of one
//    row, so sigma load and sig_n store are one float4 per 4 elements
//    (round-3 did 4 scalar loads + 4 scalar stores; issue count /4).
//  blocks [1024,5120): Q_n row + mu_n (mu_n recomputed from mu/h/scalars).
__global__ __launch_bounds__(256) void k7_fused(const float* __restrict__ Q,
                                                const float* __restrict__ sigma,
                                                const float* __restrict__ mu,
                                                const float* __restrict__ ti,
                                                float* __restrict__ out,
                                                const float* __restrict__ ws) {
    const int tid = threadIdx.x;
    const int prune = ((const int*)ws)[SC_PRUNE];
    const float inv_pu = ws[SC_INVPU];
    const float inv_pv = ws[SC_INVPV];
    const float npv = ws[SC_NPV];

    if (blockIdx.x >= 1024) {
        const int i = blockIdx.x - 1024;
        // ---- Q_n row ----
        const int pi = (i == prune) ? Mn : i;
        const bool piok = (pi < Mn);
        const float p2i = piok ? ws[OFF_Q + pi] : -1.0f;
        const float qsi = ws[OFF_QS + i];
        const float4* Qr4  = (const float4*)(Q + (size_t)pi * Mn);
        const float4* q4   = (const float4*)(ws + OFF_Q);
        const float4* qsd4 = (const float4*)(ws + OFF_QSD);
        float4* o4 = (float4*)(out + O_Q + (size_t)i * Mn);
#pragma unroll
        for (int it = 0; it < 4; ++it) {
            int u = tid + it * 256;
            float4 base = piok ? Qr4[u] : make_float4(0.f, 0.f, 0.f, 0.f);
            float4 p2j = q4[u];
            if ((prune >> 2) == u) {
                int c = prune & 3;
                ((float*)&p2j)[c] = -1.0f;
                ((float*)&base)[c] = 0.0f;
            }
            float4 d = qsd4[u];
            float4 r;
            r.x = base.x + p2i * p2j.x * inv_pu - qsi * d.x;
            r.y = base.y + p2i * p2j.y * inv_pu - qsi * d.y;
            r.z = base.z + p2i * p2j.z * inv_pu - qsi * d.z;
            r.w = base.w + p2i * p2j.w * inv_pu - qsi * d.w;
            o4[u] = r;
        }
        // ---- mu_n (4 values for this row), from mu/h + scalars ----
        if (tid < 4) {
            float tin = out[O_TI + i];
            float v;
            if (tin < 0.0f) v = 0.0f;
            else if (i == prune) v = ws[SC_MUAM + tid];
            else {
                const float sf = sqrtf(0.999f);
                v = sf * mu[tid * Mn + i] + ws[SC_DL + tid] * ws[OFF_H + i];
            }
            out[O_MU + tid * Mn + i] = v;
        }
        return;
    }

    // ---- sig_n tile (swapped-operand MFMA, float4 global access) ----
    const int t    = blockIdx.x;
    const int lane = tid & 63;
    const int w    = tid >> 6;
    const int i0 = (t >> 5) * 128 + (w >> 1) * 64;
    const int j0 = (t & 31) * 128 + (w & 1) * 64;
    const int lr = lane >> 4;
    const int lc = lane & 15;
    const uint4* db = (const uint4*)(ws + OFF_DICTB);

    // B-operand = i-block rows (n-index); i-side per-lane scalars
    bf16x8 bfI[4][2];
    float a2i_s[4], alio_s[4], ain_s[4], hr_s[4];
    bool prow_s[4];
#pragma unroll
    for (int it = 0; it < 4; ++it) {
        const int ri = i0 + it * 16 + lc;
        bfI[it][0] = __builtin_bit_cast(bf16x8, db[ri * 8 + lr]);
        bfI[it][1] = __builtin_bit_cast(bf16x8, db[ri * 8 + 4 + lr]);
        a2i_s[it]  = ws[OFF_A2 + ri];
        alio_s[it] = (ti[ri] >= 0.0f) ? 1.0f : 0.0f;
        ain_s[it]  = (out[O_TI + ri] >= 0.0f) ? 1.0f : 0.0f;
        hr_s[it]   = ws[OFF_H + ri];
        prow_s[it] = (ri == prune);
    }

#pragma unroll
    for (int jt = 0; jt < 4; ++jt) {
        const int jrow = j0 + jt * 16 + lc;       // A-operand rows (m-index)
        bf16x8 afJ0 = __builtin_bit_cast(bf16x8, db[jrow * 8 + lr]);
        bf16x8 afJ1 = __builtin_bit_cast(bf16x8, db[jrow * 8 + 4 + lr]);
        const int cb = j0 + jt * 16 + lr * 4;     // this lane's 4 consecutive cols
        const float4 a2j4 = *(const float4*)(ws + OFF_A2 + cb);
        const float4 hj4  = *(const float4*)(ws + OFF_H + cb);
        const float4 tio4 = *(const float4*)(ti + cb);
        const float4 tin4 = *(const float4*)(out + O_TI + cb);
        float a2j[4] = {a2j4.x, a2j4.y, a2j4.z, a2j4.w};
        float hj[4]  = {hj4.x, hj4.y, hj4.z, hj4.w};
        float aljo[4] = {tio4.x >= 0.f ? 1.f : 0.f, tio4.y >= 0.f ? 1.f : 0.f,
                         tio4.z >= 0.f ? 1.f : 0.f, tio4.w >= 0.f ? 1.f : 0.f};
        float ajn[4]  = {tin4.x >= 0.f ? 1.f : 0.f, tin4.y >= 0.f ? 1.f : 0.f,
                         tin4.z >= 0.f ? 1.f : 0.f, tin4.w >= 0.f ? 1.f : 0.f};
        bool pcol[4] = {cb + 0 == prune, cb + 1 == prune, cb + 2 == prune, cb + 3 == prune};
#pragma unroll
        for (int it = 0; it < 4; ++it) {
            f32x4 acc = {0.0f, 0.0f, 0.0f, 0.0f};
            acc = __builtin_amdgcn_mfma_f32_16x16x32_bf16(afJ0, bfI[it][0], acc, 0, 0, 0);
            acc = __builtin_amdgcn_mfma_f32_16x16x32_bf16(afJ1, bfI[it][1], acc, 0, 0, 0);
            const int rg = i0 + it * 16 + lc;
            const size_t off = (size_t)rg * Mn + cb;
            const float4 sv4 = *(const float4*)(sigma + off);
            float sv[4] = {sv4.x, sv4.y, sv4.z, sv4.w};
            float res[4];
#pragma unroll
            for (int e = 0; e < 4; ++e) {
                float d2 = fmaxf(a2i_s[it] + a2j[e] - 2.0f * acc[e], 0.0f);
                float kv = __expf(d2 * (-1.0f / 128.0f)) * alio_s[it] * aljo[e];
                float bs = 0.999f * sv[e] + 0.001f * kv;
                if (pcol[e])    bs = prow_s[it] ? npv : hr_s[it];
                if (prow_s[it]) bs = pcol[e] ? npv : hj[e];
                float p_i = prow_s[it] ? npv : hr_s[it];
                float p_j = pcol[e] ? npv : hj[e];
                res[e] = ain_s[it] * ajn[e] * (bs - p_i * p_j * inv_pv);
            }
            float4 r4 = {res[0], res[1], res[2], res[3]};
            *(float4*)(out + O_SIG + off) = r4;
        }
    }
}

extern "C" void kernel_launch(void* const* d_in, const int* in_sizes, int n_in,
                              void* d_out, int out_size, void* d_ws, size_t ws_size,
                              hipStream_t stream) {
    const float* dict  = (const float*)d_in[0];
    const float* mu    = (const float*)d_in[1];
    const float* sigma = (const float*)d_in[2];
    const float* Q     = (const float*)d_in[3];
    const float* x     = (const float*)d_in[4];
    const float* y     = (const float*)d_in[5];
    const float* nn    = (const float*)d_in[6];
    const float* nd    = (const float*)d_in[7];
    const float* ti    = (const float*)d_in[8];
    const int*   tptr  = (const int*)d_in[9];
    float* out = (float*)d_out;
    float* ws  = (float*)d_ws;

    k1_prep<<<1024, 256, 0, stream>>>(dict, x, ti, ws);
    k2_q<<<4096, 256, 0, stream>>>(Q, ws);
    k3_h<<<2048, 256, 0, stream>>>(sigma, ti, ws);
    k4_scalars<<<1, 1024, 0, stream>>>(mu, y, nn, nd, ws, out);
    k5_crit<<<1024, 256, 0, stream>>>(Q, mu, ti, ws);
    k6_argmin<<<1, 1024, 0, stream>>>(Q, ti, ws);
    k6b_vec<<<1024, 256, 0, stream>>>(Q, dict, x, ti, tptr, ws, out);
    k7_fused<<<5120, 256, 0, stream>>>(Q, sigma, mu, ti, out, ws);
}